// Round 4
// baseline (18398.979 us; speedup 1.0000x reference)
//
#include <hip/hip_runtime.h>
#include <stdint.h>

// LSTM(relu) persistent kernel v4: B=64,S=1024,F=128,H=512.
// 512 wgs x 64 threads = 512 waves, exactly 2 per CU, no LDS, no __syncthreads.
// Wave (grp, wid): 4 units (u0=wid*4) x 16 batch rows (grp*16..+15).
// Resident register set kept SMALL so hipcc won't spill (v2/v3 lesson):
//   au[20] = 80 VGPR ([U;W]^T A-frags), 1 acc tile, bh transient.
// Swapped MFMA (z^T = [U;W]^T [h;x]^T): D reg r = gate r, unit = u0+l4,
// batch row = l15 -> gate combine fully register-local.
// h exchange: double-buffered global bf16 + per-wave release flag (64B apart);
// consumers poll all 128 group flags with 2 lane-parallel loads + __all.
// Group->XCD affinity: grp = (blk&7)>>1 (round-robin dispatch heuristic).

#define B_ 64
#define S_ 1024
#define F_ 128
#define H_ 512
#define G4_ 2048
#define GROUPS 4
#define BG_ 16          // batch rows per group
#define WPG 128         // waves per group
#define UW 4            // units per wave
#define KH 16           // h@U K-steps (512/32)
#define KX 4            // x@W K-steps (128/32)
#define KT 20
#define HBUF_ELEMS (B_ * H_)

typedef __attribute__((ext_vector_type(8))) short short8;  // 8 x bf16
typedef __attribute__((ext_vector_type(4))) float f32x4;

__device__ __forceinline__ unsigned short f2bf(float f) {
  union { float f; unsigned u; } v; v.f = f;
  unsigned u = v.u + 0x7fffu + ((v.u >> 16) & 1u);   // RNE
  return (unsigned short)(u >> 16);
}

__device__ __forceinline__ short8 pack2(f32x4 a, f32x4 b) {
  short8 r;
#pragma unroll
  for (int i = 0; i < 4; ++i) r[i] = (short)f2bf(a[i]);
#pragma unroll
  for (int i = 0; i < 4; ++i) r[4 + i] = (short)f2bf(b[i]);
  return r;
}

__global__ __launch_bounds__(64, 2) void lstm_pers(
    const float* __restrict__ x, const float* __restrict__ W,
    const float* __restrict__ U, const float* __restrict__ bias,
    float* __restrict__ out, unsigned int* flags, unsigned short* hbuf) {

  const int lane = threadIdx.x;        // one wave per wg
  const int l15  = lane & 15;
  const int l4   = lane >> 4;          // 0..3
  const int koff = l4 * 8;

  const int blk = blockIdx.x;          // 0..511
  const int x8  = blk & 7;             // XCD id under round-robin dispatch
  const int grp = x8 >> 1;             // batch group -> 2 XCDs per group
  const int wid = ((blk >> 3) << 1) | (x8 & 1);   // 0..127 wave-in-group
  const int u0  = wid * UW;
  const int bbase = grp * BG_;

  unsigned int* gflags = flags + (size_t)grp * WPG * 16;  // 64B-spaced
  unsigned int* myflag = gflags + wid * 16;
  unsigned int* pf0    = gflags + lane * 16;
  unsigned int* pf1    = gflags + (lane + 64) * 16;

  // ---- one-time: [U;W]^T A-fragments into registers (80 VGPR) ----
  // A[m = l15][k = koff+jj] = M[k][zcol(m)], zcol(m) = (m&3)*H + u0 + (m>>2)
  const int gate_a = l15 & 3;
  const int usub_a = l15 >> 2;
  const int zcol   = gate_a * H_ + u0 + usub_a;
  short8 au[KT];
#pragma unroll
  for (int ks = 0; ks < KT; ++ks) {
    short8 v;
#pragma unroll
    for (int jj = 0; jj < 8; ++jj) {
      const int k = ks * 32 + koff + jj;
      const float f = (ks < KH) ? U[(size_t)k * G4_ + zcol]
                                : W[(size_t)(k - H_) * G4_ + zcol];
      v[jj] = (short)f2bf(f);
    }
    au[ks] = v;
  }

  // D-side mapping: reg r = gate r, unit = u0 + l4, batch row = bbase + l15
  float bias_r[4];
#pragma unroll
  for (int g = 0; g < 4; ++g) bias_r[g] = bias[g * H_ + u0 + l4];

  float cstate = 0.f;
  const float* xrow = x + ((size_t)(bbase + l15) * S_) * F_ + koff;
  const unsigned short* hrow0 = hbuf + (size_t)(bbase + l15) * H_ + koff;
  const int brow = bbase + l15;
  const int unit = u0 + l4;

  for (int t = 0; t < S_; ++t) {
    // ---- issue x f32 loads first: latency hides under the poll spin ----
    const float* xt = xrow + (size_t)t * F_;
    f32x4 xa[KX], xb[KX];
#pragma unroll
    for (int q = 0; q < KX; ++q) {
      xa[q] = *(const f32x4*)(xt + q * 32);
      xb[q] = *(const f32x4*)(xt + q * 32 + 4);
    }

    // ---- wait for h(t-1) from all 128 waves of this group ----
    if (t > 0) {
      const unsigned tgt = (unsigned)t;
      while (true) {
        unsigned a = __hip_atomic_load(pf0, __ATOMIC_RELAXED, __HIP_MEMORY_SCOPE_AGENT);
        unsigned b = __hip_atomic_load(pf1, __ATOMIC_RELAXED, __HIP_MEMORY_SCOPE_AGENT);
        if (__all((int)((a >= tgt) & (b >= tgt)))) break;
      }
      (void)__hip_atomic_load(myflag, __ATOMIC_ACQUIRE, __HIP_MEMORY_SCOPE_AGENT);
    }

    // ---- issue all h B-frag loads (latency hidden by x@W MFMAs) ----
    short8 bh0[8], bh1[8];
    if (t > 0) {
      const unsigned short* hr = hrow0 + (size_t)(t & 1) * HBUF_ELEMS;
#pragma unroll
      for (int ks = 0; ks < 8; ++ks) bh0[ks] = *(const short8*)(hr + ks * 32);
#pragma unroll
      for (int ks = 0; ks < 8; ++ks) bh1[ks] = *(const short8*)(hr + (ks + 8) * 32);
    }

    // ---- acc = bias; x @ W while h loads are in flight ----
    f32x4 acc, acc1;
    acc[0] = bias_r[0]; acc[1] = bias_r[1]; acc[2] = bias_r[2]; acc[3] = bias_r[3];
    acc1[0] = 0.f; acc1[1] = 0.f; acc1[2] = 0.f; acc1[3] = 0.f;
#pragma unroll
    for (int q = 0; q < KX; ++q) {
      short8 bx = pack2(xa[q], xb[q]);
      acc = __builtin_amdgcn_mfma_f32_16x16x32_bf16(au[KH + q], bx, acc, 0, 0, 0);
    }

    // ---- h(t-1) @ U : two independent accumulate chains ----
    if (t > 0) {
#pragma unroll
      for (int ks = 0; ks < 8; ++ks)
        acc  = __builtin_amdgcn_mfma_f32_16x16x32_bf16(au[ks],     bh0[ks], acc,  0, 0, 0);
#pragma unroll
      for (int ks = 0; ks < 8; ++ks)
        acc1 = __builtin_amdgcn_mfma_f32_16x16x32_bf16(au[8 + ks], bh1[ks], acc1, 0, 0, 0);
    }
    acc[0] += acc1[0]; acc[1] += acc1[1]; acc[2] += acc1[2]; acc[3] += acc1[3];

    // ---- gates: regs 0..3 = i,f,g,o of this lane's (row, unit) ----
    const float zi = acc[0], zf = acc[1], zg = acc[2], zo = acc[3];
    const float ig = 1.f / (1.f + __expf(-zi));
    const float fg = 1.f / (1.f + __expf(-zf));
    const float gg = fmaxf(zg, 0.f);               // relu candidate
    const float og = 1.f / (1.f + __expf(-zo));
    const float cn = fg * cstate + ig * gg;
    cstate = cn;
    const float h = og * fmaxf(cn, 0.f);           // relu output activation

    // ---- publish h, then flag (release waits only on the h store),
    //      then the out store drains off the critical path ----
    unsigned short* hw = hbuf + (size_t)((t + 1) & 1) * HBUF_ELEMS;
    hw[(size_t)brow * H_ + unit] = f2bf(h);
    if (lane == 0)
      __hip_atomic_store(myflag, (unsigned)(t + 1), __ATOMIC_RELEASE, __HIP_MEMORY_SCOPE_AGENT);
    __builtin_nontemporal_store(h, &out[((size_t)brow * S_ + t) * H_ + unit]);
  }
}

extern "C" void kernel_launch(void* const* d_in, const int* in_sizes, int n_in,
                              void* d_out, int out_size, void* d_ws, size_t ws_size,
                              hipStream_t stream) {
  const float* x = (const float*)d_in[0];
  const float* W = (const float*)d_in[1];
  const float* U = (const float*)d_in[2];
  const float* b = (const float*)d_in[3];
  float* out = (float*)d_out;

  unsigned int*   flags = (unsigned int*)d_ws;                     // 4*128 flags, 64B apart = 32KB
  unsigned short* hbuf  = (unsigned short*)((char*)d_ws + 32768);  // 2 x 64 x 512 bf16 = 256KB

  hipMemsetAsync(d_ws, 0, 32768, stream);   // zero flags each launch/replay

  lstm_pers<<<dim3(GROUPS * WPG), dim3(64), 0, stream>>>(x, W, U, b, out, flags, hbuf);
}

// Round 5
// 3517.762 us; speedup vs baseline: 5.2303x; 5.2303x over previous
//
#include <hip/hip_runtime.h>
#include <stdint.h>

// LSTM(relu) persistent kernel v5: B=64,S=1024,F=128,H=512.
// 256 wgs x 64 thr (1 wave), 82KB LDS -> exactly 1 wg/CU, all co-resident.
// 8 batch-groups of 8 rows, ONE GROUP PER XCD: group id = HW_REG_XCC_ID
// (s_getreg), slot 0..31 claimed via atomicAdd -> robust to any blk->XCD map
// (pigeonhole: 256 single-wave 82KB wgs on 256 CUs = exactly 32 per XCD).
// Weights [U;W]^T live in LDS as bf16 (64 zcols x 640 k, XOR-swizzled);
// z^T = [U;W]^T [h;x]^T via mfma_16x16x32_bf16, D reg r = gate r (validated).
// Sync is XCD-LOCAL through the shared per-XCD L2: producers store h,
// s_waitcnt vmcnt(0), relaxed flag store; consumers poll + read h with
// RELAXED agent atomic loads (sc0 = L1 bypass). No acquire/release -> no
// buffer_inv / L2 writeback storms (the v2-v4 killer).

#define S_ 1024
#define F_ 128
#define H_ 512
#define G4_ 2048
#define RG 8            // batch rows per group
#define SLOTS 32        // wgs per group (= CUs per XCD)
#define KH 16           // h@U K-steps (512/32)
#define KX 4            // x@W K-steps (128/32)
#define LDKS 640        // shorts per LDS weight row (k dim)
#define HB (64 * H_)    // one h buffer: 64 rows x 512 units

typedef __attribute__((ext_vector_type(8))) short short8;  // 8 x bf16
typedef __attribute__((ext_vector_type(4))) float f32x4;
typedef unsigned long long ull;

__device__ __forceinline__ unsigned short f2bf(float f) {
  union { float f; unsigned u; } v; v.f = f;
  unsigned u = v.u + 0x7fffu + ((v.u >> 16) & 1u);   // RNE
  return (unsigned short)(u >> 16);
}

__device__ __forceinline__ short8 pack2(f32x4 a, f32x4 b) {
  short8 r;
#pragma unroll
  for (int i = 0; i < 4; ++i) r[i] = (short)f2bf(a[i]);
#pragma unroll
  for (int i = 0; i < 4; ++i) r[4 + i] = (short)f2bf(b[i]);
  return r;
}

// swizzled short-index into V: rows (cc) stride LDKS (640, mult of 64);
// XOR of bits 3..5 stays within a row and preserves 8-short chunks.
__device__ __forceinline__ int swz(int cc, int k) {
  return (cc * LDKS + k) ^ ((cc & 7) << 3);
}

__global__ __launch_bounds__(64, 1) void lstm_pers(
    const float* __restrict__ x, const float* __restrict__ W,
    const float* __restrict__ U, const float* __restrict__ bias,
    float* __restrict__ out, unsigned int* ws_sync, unsigned short* hbuf) {

  __shared__ unsigned short V[64 * LDKS];   // 81920 B -> 1 wg/CU

  const int lane = threadIdx.x;
  const int l15  = lane & 15;
  const int l4   = lane >> 4;
  const int koff = l4 * 8;

  // ---- physical XCD id + slot claim (robust group formation) ----
  unsigned int xcc;
  asm volatile("s_getreg_b32 %0, hwreg(20, 0, 4)" : "=s"(xcc));  // HW_REG_XCC_ID
  xcc &= 7;
  unsigned int sv = 0;
  if (lane == 0) sv = atomicAdd(ws_sync + xcc * 32, 1u);         // 128B-spaced ctrs
  const int slot = __shfl((int)sv, 0) & 31;

  unsigned int* flags  = ws_sync + 256;                  // flags at +1024B
  unsigned int* gflags = flags + (int)xcc * SLOTS * 16;  // 64B-spaced
  unsigned int* myflag = gflags + slot * 16;
  unsigned int* pollp  = gflags + (lane & 31) * 16;

  const int u0    = slot * 16;       // 16 units per wg
  const int bbase = (int)xcc * RG;   // 8 batch rows per group

  // ---- LDS fill: V[cc][k] = bf16(M[k][zcol]), zcol(c,tl)=(c&3)*H+u0+tl*4+(c>>2),
  //      cc = tl*16 + c. Storage loop runs over (gate, unit) so global loads are f32x4.
  for (int idx = lane; idx < (64 * LDKS) / 4; idx += 64) {
    const int q4  = idx & 15;
    const int k   = idx >> 4;                 // 0..639
    const int gate = q4 & 3;
    const int ul0  = (q4 >> 2) * 4;           // 0,4,8,12
    const int col  = gate * H_ + u0 + ul0;
    const float* src = (k < H_) ? (U + (size_t)k * G4_ + col)
                                : (W + (size_t)(k - H_) * G4_ + col);
    const f32x4 v4 = *(const f32x4*)src;
#pragma unroll
    for (int q = 0; q < 4; ++q) {
      const int ul = ul0 + q;
      const int cc = (ul >> 2) * 16 + (ul & 3) * 4 + gate;
      V[swz(cc, k)] = f2bf(v4[q]);
    }
  }

  float bias_r[4][4];   // [tile][gate]
#pragma unroll
  for (int tl = 0; tl < 4; ++tl)
#pragma unroll
    for (int g = 0; g < 4; ++g)
      bias_r[tl][g] = bias[g * H_ + u0 + tl * 4 + l4];

  __syncthreads();

  const int brow = bbase + (l15 & 7);        // rows duplicated for l15>=8 (cols discarded)
  const float* xrow = x + (size_t)brow * S_ * F_ + koff;
  const unsigned short* hrow0 = hbuf + (size_t)brow * H_ + koff;

  float cst[4] = {0.f, 0.f, 0.f, 0.f};

  for (int t = 0; t < S_; ++t) {
    // ---- x f32 loads first: complete while we spin on flags ----
    const float* xt = xrow + (size_t)t * F_;
    f32x4 xa[KX], xb[KX];
#pragma unroll
    for (int q = 0; q < KX; ++q) {
      xa[q] = *(const f32x4*)(xt + q * 32);
      xb[q] = *(const f32x4*)(xt + q * 32 + 4);
    }

    if (t > 0) {
      // ---- poll the 32 slot flags of THIS XCD (lane-parallel, sc0->L2) ----
      const unsigned tgt = (unsigned)t;
      while (true) {
        unsigned v = __hip_atomic_load(pollp, __ATOMIC_RELAXED, __HIP_MEMORY_SCOPE_AGENT);
        if (__all((int)(v >= tgt))) break;
      }
      asm volatile("" ::: "memory");   // keep h loads below the poll
    }

    // ---- h(t-1) B-frags: relaxed agent (sc0) loads from the shared L2 ----
    short8 bh[KH];
    if (t > 0) {
      const unsigned short* hr = hrow0 + (size_t)(t & 1) * HB;
#pragma unroll
      for (int ks = 0; ks < KH; ++ks) {
        union { ull u[2]; short8 s; } bb;
        const ull* hq = (const ull*)(hr + ks * 32);
        bb.u[0] = __hip_atomic_load(hq,     __ATOMIC_RELAXED, __HIP_MEMORY_SCOPE_AGENT);
        bb.u[1] = __hip_atomic_load(hq + 1, __ATOMIC_RELAXED, __HIP_MEMORY_SCOPE_AGENT);
        bh[ks] = bb.s;
      }
    }

    // ---- acc = bias ----
    f32x4 acc[4];
#pragma unroll
    for (int tl = 0; tl < 4; ++tl) {
      f32x4 a;
      a[0] = bias_r[tl][0]; a[1] = bias_r[tl][1];
      a[2] = bias_r[tl][2]; a[3] = bias_r[tl][3];
      acc[tl] = a;
    }

    // ---- x @ W (LDS k rows 512..639) — runs while h loads are in flight ----
#pragma unroll
    for (int q = 0; q < KX; ++q) {
      const short8 bx = pack2(xa[q], xb[q]);
      const int k0 = (KH + q) * 32 + koff;
#pragma unroll
      for (int tl = 0; tl < 4; ++tl) {
        const short8 a = *(const short8*)&V[swz(tl * 16 + l15, k0)];
        acc[tl] = __builtin_amdgcn_mfma_f32_16x16x32_bf16(a, bx, acc[tl], 0, 0, 0);
      }
    }

    // ---- h(t-1) @ U (LDS k rows 0..511) ----
    if (t > 0) {
#pragma unroll
      for (int ks = 0; ks < KH; ++ks) {
        const int k0 = ks * 32 + koff;
#pragma unroll
        for (int tl = 0; tl < 4; ++tl) {
          const short8 a = *(const short8*)&V[swz(tl * 16 + l15, k0)];
          acc[tl] = __builtin_amdgcn_mfma_f32_16x16x32_bf16(a, bh[ks], acc[tl], 0, 0, 0);
        }
      }
    }

    // ---- gates (reg r = gate r of one (row,unit)); h store; publish; out ----
    unsigned short* hw = hbuf + (size_t)((t + 1) & 1) * HB + (size_t)brow * H_;
    float* orow = out + ((size_t)brow * S_ + t) * H_;
    float hv[4];
#pragma unroll
    for (int tl = 0; tl < 4; ++tl) {
      const float zi = acc[tl][0], zf = acc[tl][1], zg = acc[tl][2], zo = acc[tl][3];
      const float ig = 1.f / (1.f + __expf(-zi));
      const float fg = 1.f / (1.f + __expf(-zf));
      const float gg = fmaxf(zg, 0.f);               // relu candidate
      const float og = 1.f / (1.f + __expf(-zo));
      const float cn = fg * cst[tl] + ig * gg;
      cst[tl] = cn;
      hv[tl] = og * fmaxf(cn, 0.f);                  // relu output activation
      if (l15 < 8) hw[u0 + tl * 4 + l4] = f2bf(hv[tl]);
    }

    // h stores complete at L2, then flag; out stores stay OFF the publish path
    asm volatile("s_waitcnt vmcnt(0)" ::: "memory");
    if (lane == 0)
      __hip_atomic_store(myflag, (unsigned)(t + 1), __ATOMIC_RELAXED, __HIP_MEMORY_SCOPE_AGENT);
    if (l15 < 8) {
#pragma unroll
      for (int tl = 0; tl < 4; ++tl)
        orow[u0 + tl * 4 + l4] = hv[tl];
    }
  }
}

extern "C" void kernel_launch(void* const* d_in, const int* in_sizes, int n_in,
                              void* d_out, int out_size, void* d_ws, size_t ws_size,
                              hipStream_t stream) {
  const float* x = (const float*)d_in[0];
  const float* W = (const float*)d_in[1];
  const float* U = (const float*)d_in[2];
  const float* b = (const float*)d_in[3];
  float* out = (float*)d_out;

  unsigned int*   ws_sync = (unsigned int*)d_ws;                    // ctrs(1KB) + flags(16KB)
  unsigned short* hbuf    = (unsigned short*)((char*)d_ws + 32768); // 2 x 64 x 512 bf16 = 128KB

  hipMemsetAsync(d_ws, 0, 32768, stream);   // zero slot ctrs + flags each launch/replay

  lstm_pers<<<dim3(256), dim3(64), 0, stream>>>(x, W, U, b, out, ws_sync, hbuf);
}

// Round 6
// 3030.230 us; speedup vs baseline: 6.0718x; 1.1609x over previous
//
#include <hip/hip_runtime.h>
#include <stdint.h>

// LSTM(relu) persistent kernel v6: B=64,S=1024,F=128,H=512.
// v5 structure (XCD-local groups, fence-free L2 sync, LDS weights) but the
// per-step K dim is SPLIT ACROSS 4 WAVES of a 256-thread wg to hide latency
// (v5 was 1 wave/CU: ~85% of each 8300-cyc step was exposed memory latency).
// Wave w: h-K-steps {4w..4w+3}, x-K-step {w} -> 20 MFMA + 20 ds_read_b128 +
// 8 h-loads each, concurrent on the CU's 4 SIMDs. Partials reduced via a
// 12KB LDS buffer; wave 0 does poll, reduce, gates, stores, publish.
// 256 wgs x 256 thr, 94KB LDS -> exactly 1 wg/CU (XCD pigeonhole intact).

#define S_ 1024
#define F_ 128
#define H_ 512
#define G4_ 2048
#define SLOTS 32        // wgs per XCD group
#define KH 16           // h@U K-steps (512/32)
#define LDKS 640        // shorts per LDS weight row (k dim)
#define HB (64 * H_)    // one h buffer: 64 rows x 512 units

typedef __attribute__((ext_vector_type(8))) short short8;  // 8 x bf16
typedef __attribute__((ext_vector_type(4))) float f32x4;
typedef unsigned long long ull;

__device__ __forceinline__ unsigned short f2bf(float f) {
  union { float f; unsigned u; } v; v.f = f;
  unsigned u = v.u + 0x7fffu + ((v.u >> 16) & 1u);   // RNE
  return (unsigned short)(u >> 16);
}

__device__ __forceinline__ short8 pack2(f32x4 a, f32x4 b) {
  short8 r;
#pragma unroll
  for (int i = 0; i < 4; ++i) r[i] = (short)f2bf(a[i]);
#pragma unroll
  for (int i = 0; i < 4; ++i) r[4 + i] = (short)f2bf(b[i]);
  return r;
}

// swizzled short-index into V (validated in v5)
__device__ __forceinline__ int swz(int cc, int k) {
  return (cc * LDKS + k) ^ ((cc & 7) << 3);
}

__global__ __launch_bounds__(256, 1) void lstm_pers(
    const float* __restrict__ x, const float* __restrict__ W,
    const float* __restrict__ U, const float* __restrict__ bias,
    float* __restrict__ out, unsigned int* ws_sync, unsigned short* hbuf) {

  __shared__ unsigned short V[64 * LDKS];   // 81920 B
  __shared__ f32x4 R[3][4][64];             // 12288 B partial-acc staging
  __shared__ int meta[2];

  const int tid  = threadIdx.x;
  const int w    = tid >> 6;           // wave 0..3
  const int lane = tid & 63;
  const int l15  = lane & 15;
  const int l4   = lane >> 4;
  const int koff = l4 * 8;

  // ---- physical XCD id + slot claim (robust group formation, as v5) ----
  if (tid == 0) {
    unsigned int xcc;
    asm volatile("s_getreg_b32 %0, hwreg(20, 0, 4)" : "=s"(xcc));  // HW_REG_XCC_ID
    xcc &= 7;
    unsigned sv = atomicAdd(ws_sync + xcc * 32, 1u);   // 128B-spaced ctrs
    meta[0] = (int)xcc;
    meta[1] = (int)(sv & 31);
  }
  __syncthreads();
  const int xcc  = meta[0];
  const int slot = meta[1];

  unsigned int* flags  = ws_sync + 256;                  // flags at +1024B
  unsigned int* gflags = flags + xcc * SLOTS * 16;       // 64B-spaced
  unsigned int* myflag = gflags + slot * 16;
  unsigned int* pollp  = gflags + (lane & 31) * 16;

  const int u0    = slot * 16;       // 16 units per wg
  const int bbase = xcc * 8;         // 8 batch rows per group

  // ---- LDS fill (identical decomposition to v5, 256-thread stride) ----
  for (int idx = tid; idx < (64 * LDKS) / 4; idx += 256) {
    const int q4   = idx & 15;
    const int k    = idx >> 4;                // 0..639
    const int gate = q4 & 3;
    const int ul0  = (q4 >> 2) * 4;           // 0,4,8,12
    const int col  = gate * H_ + u0 + ul0;
    const float* src = (k < H_) ? (U + (size_t)k * G4_ + col)
                                : (W + (size_t)(k - H_) * G4_ + col);
    const f32x4 v4 = *(const f32x4*)src;
#pragma unroll
    for (int q = 0; q < 4; ++q) {
      const int ul = ul0 + q;
      const int cc = (ul >> 2) * 16 + (ul & 3) * 4 + gate;
      V[swz(cc, k)] = f2bf(v4[q]);
    }
  }

  float bias_r[4][4];   // [tile][gate], wave 0 only
  if (w == 0) {
#pragma unroll
    for (int tl = 0; tl < 4; ++tl)
#pragma unroll
      for (int g = 0; g < 4; ++g)
        bias_r[tl][g] = bias[g * H_ + u0 + tl * 4 + l4];
  }

  __syncthreads();

  const int brow = bbase + (l15 & 7);   // rows duplicated for l15>=8
  const float* xrow = x + (size_t)brow * S_ * F_ + koff + w * 32;
  const unsigned short* hrow0 = hbuf + (size_t)brow * H_ + koff;

  float cst[4] = {0.f, 0.f, 0.f, 0.f};  // wave 0 only

  for (int t = 0; t < S_; ++t) {
    // ---- every wave: its x slice, issued before any waiting ----
    const float* xt = xrow + (size_t)t * F_;
    const f32x4 xa = *(const f32x4*)(xt);
    const f32x4 xb = *(const f32x4*)(xt + 4);

    // ---- wave 0 polls the 32 slot flags of THIS XCD ----
    if (t > 0 && w == 0) {
      const unsigned tgt = (unsigned)t;
      while (true) {
        unsigned v = __hip_atomic_load(pollp, __ATOMIC_RELAXED, __HIP_MEMORY_SCOPE_AGENT);
        if (__all((int)(v >= tgt))) break;
      }
    }
    __syncthreads();   // barrier1: h(t-1) now safe for all waves to read

    // ---- wave w's h B-frags (k-steps 4w..4w+3), sc0 loads from shared L2 ----
    short8 bh[4];
    if (t > 0) {
      const unsigned short* hr = hrow0 + (size_t)(t & 1) * HB;
#pragma unroll
      for (int i = 0; i < 4; ++i) {
        union { ull u[2]; short8 s; } bb;
        const ull* hq = (const ull*)(hr + (4 * w + i) * 32);
        bb.u[0] = __hip_atomic_load(hq,     __ATOMIC_RELAXED, __HIP_MEMORY_SCOPE_AGENT);
        bb.u[1] = __hip_atomic_load(hq + 1, __ATOMIC_RELAXED, __HIP_MEMORY_SCOPE_AGENT);
        bh[i] = bb.s;
      }
    }

    // ---- partial acc: wave0 carries bias, others zero ----
    f32x4 acc[4];
#pragma unroll
    for (int tl = 0; tl < 4; ++tl) {
      f32x4 a;
      if (w == 0) {
        a[0] = bias_r[tl][0]; a[1] = bias_r[tl][1];
        a[2] = bias_r[tl][2]; a[3] = bias_r[tl][3];
      } else {
        a[0] = 0.f; a[1] = 0.f; a[2] = 0.f; a[3] = 0.f;
      }
      acc[tl] = a;
    }

    // ---- x @ W : this wave's single x K-step (LDS rows (KH+w)*32..) ----
    {
      const short8 bx = pack2(xa, xb);
      const int k0 = (KH + w) * 32 + koff;
#pragma unroll
      for (int tl = 0; tl < 4; ++tl) {
        const short8 a = *(const short8*)&V[swz(tl * 16 + l15, k0)];
        acc[tl] = __builtin_amdgcn_mfma_f32_16x16x32_bf16(a, bx, acc[tl], 0, 0, 0);
      }
    }

    // ---- h(t-1) @ U : this wave's 4 h K-steps ----
    if (t > 0) {
#pragma unroll
      for (int i = 0; i < 4; ++i) {
        const int k0 = (4 * w + i) * 32 + koff;
#pragma unroll
        for (int tl = 0; tl < 4; ++tl) {
          const short8 a = *(const short8*)&V[swz(tl * 16 + l15, k0)];
          acc[tl] = __builtin_amdgcn_mfma_f32_16x16x32_bf16(a, bh[i], acc[tl], 0, 0, 0);
        }
      }
    }

    // ---- stage partials (waves 1..3), then combine on wave 0 ----
    if (w > 0) {
#pragma unroll
      for (int tl = 0; tl < 4; ++tl) R[w - 1][tl][lane] = acc[tl];
    }
    __syncthreads();   // barrier2: partials visible
    // (single-buffered R is safe: next-step writes are gated by barrier1(t+1),
    //  which wave 0 only reaches after finishing this reduce.)

    if (w == 0) {
#pragma unroll
      for (int ww = 0; ww < 3; ++ww)
#pragma unroll
        for (int tl = 0; tl < 4; ++tl) {
          const f32x4 r = R[ww][tl][lane];
          acc[tl][0] += r[0]; acc[tl][1] += r[1];
          acc[tl][2] += r[2]; acc[tl][3] += r[3];
        }

      // ---- gates (reg r = gate r of one (row,unit)), h store, publish, out ----
      unsigned short* hw = hbuf + (size_t)((t + 1) & 1) * HB + (size_t)brow * H_;
      float* orow = out + ((size_t)brow * S_ + t) * H_;
      float hv[4];
#pragma unroll
      for (int tl = 0; tl < 4; ++tl) {
        const float zi = acc[tl][0], zf = acc[tl][1], zg = acc[tl][2], zo = acc[tl][3];
        const float ig = 1.f / (1.f + __expf(-zi));
        const float fg = 1.f / (1.f + __expf(-zf));
        const float gg = fmaxf(zg, 0.f);               // relu candidate
        const float og = 1.f / (1.f + __expf(-zo));
        const float cn = fg * cst[tl] + ig * gg;
        cst[tl] = cn;
        hv[tl] = og * fmaxf(cn, 0.f);                  // relu output activation
        if (l15 < 8) hw[u0 + tl * 4 + l4] = f2bf(hv[tl]);
      }

      // h stores complete at L2, then flag; out stores off the publish path
      asm volatile("s_waitcnt vmcnt(0)" ::: "memory");
      if (lane == 0)
        __hip_atomic_store(myflag, (unsigned)(t + 1), __ATOMIC_RELAXED, __HIP_MEMORY_SCOPE_AGENT);
      if (l15 < 8) {
#pragma unroll
        for (int tl = 0; tl < 4; ++tl)
          orow[u0 + tl * 4 + l4] = hv[tl];
      }
    }
  }
}

extern "C" void kernel_launch(void* const* d_in, const int* in_sizes, int n_in,
                              void* d_out, int out_size, void* d_ws, size_t ws_size,
                              hipStream_t stream) {
  const float* x = (const float*)d_in[0];
  const float* W = (const float*)d_in[1];
  const float* U = (const float*)d_in[2];
  const float* b = (const float*)d_in[3];
  float* out = (float*)d_out;

  unsigned int*   ws_sync = (unsigned int*)d_ws;                    // ctrs(1KB) + flags(16KB)
  unsigned short* hbuf    = (unsigned short*)((char*)d_ws + 32768); // 2 x 64 x 512 bf16 = 128KB

  hipMemsetAsync(d_ws, 0, 32768, stream);   // zero slot ctrs + flags each launch/replay

  lstm_pers<<<dim3(256), dim3(256), 0, stream>>>(x, W, U, b, out, ws_sync, hbuf);
}

// Round 7
// 2627.314 us; speedup vs baseline: 7.0030x; 1.1534x over previous
//
#include <hip/hip_runtime.h>
#include <stdint.h>

// LSTM(relu) persistent kernel v7: B=64,S=1024,F=128,H=512.
// v6 structure (XCD-local groups via HW_REG_XCC_ID, fence-free L2 sync,
// LDS-resident [U;W]^T, 4-wave K-split) with the serial tail parallelized:
//  - wave w owns tile w's reduce + gates + h/out stores (v6: all on wave 0)
//  - per-group flags packed in ONE 128B line -> poll is 1 coalesced load
//  - x@W runs BEFORE the poll (h-independent); x(t+1) loads issued under h@U
//  - per-wave vmcnt(0) then barrier3 then single flag store; out after flag
// 256 wgs x 256 thr, ~98KB LDS -> exactly 1 wg/CU (XCD pigeonhole intact).

#define S_ 1024
#define F_ 128
#define H_ 512
#define G4_ 2048
#define SLOTS 32        // wgs per XCD group
#define KH 16           // h@U K-steps (512/32)
#define LDKS 640        // shorts per LDS weight row (k dim)
#define HB (64 * H_)    // one h buffer: 64 rows x 512 units

typedef __attribute__((ext_vector_type(8))) short short8;  // 8 x bf16
typedef __attribute__((ext_vector_type(4))) float f32x4;
typedef unsigned long long ull;

__device__ __forceinline__ unsigned short f2bf(float f) {
  union { float f; unsigned u; } v; v.f = f;
  unsigned u = v.u + 0x7fffu + ((v.u >> 16) & 1u);   // RNE
  return (unsigned short)(u >> 16);
}

__device__ __forceinline__ short8 pack2(f32x4 a, f32x4 b) {
  short8 r;
#pragma unroll
  for (int i = 0; i < 4; ++i) r[i] = (short)f2bf(a[i]);
#pragma unroll
  for (int i = 0; i < 4; ++i) r[4 + i] = (short)f2bf(b[i]);
  return r;
}

// swizzled short-index into V (validated in v5/v6)
__device__ __forceinline__ int swz(int cc, int k) {
  return (cc * LDKS + k) ^ ((cc & 7) << 3);
}

__global__ __launch_bounds__(256, 1) void lstm_pers(
    const float* __restrict__ x, const float* __restrict__ W,
    const float* __restrict__ U, const float* __restrict__ bias,
    float* __restrict__ out, unsigned int* ws_sync, unsigned short* hbuf) {

  __shared__ unsigned short V[64 * LDKS];   // 81920 B
  __shared__ f32x4 R[4][4][64];             // 16384 B partial-acc staging
  __shared__ int meta[2];

  const int tid  = threadIdx.x;
  const int w    = tid >> 6;           // wave 0..3 (owns tile w)
  const int lane = tid & 63;
  const int l15  = lane & 15;
  const int l4   = lane >> 4;
  const int koff = l4 * 8;

  // ---- physical XCD id + slot claim (robust group formation) ----
  if (tid == 0) {
    unsigned int xcc;
    asm volatile("s_getreg_b32 %0, hwreg(20, 0, 4)" : "=s"(xcc));  // HW_REG_XCC_ID
    xcc &= 7;
    unsigned sv = atomicAdd(ws_sync + xcc * 32, 1u);   // 128B-spaced ctrs
    meta[0] = (int)xcc;
    meta[1] = (int)(sv & 31);
  }
  __syncthreads();
  const int xcc  = meta[0];
  const int slot = meta[1];

  // flags: ONE 128B line per group, 4B per slot
  unsigned int* flags  = ws_sync + 256;             // +1024B
  unsigned int* gline  = flags + xcc * 32;          // this group's 128B line
  unsigned int* myflag = gline + slot;
  unsigned int* pollp  = gline + (lane & 31);

  const int u0    = slot * 16;       // 16 units per wg
  const int bbase = xcc * 8;         // 8 batch rows per group

  // ---- LDS fill (identical decomposition to v5/v6) ----
  for (int idx = tid; idx < (64 * LDKS) / 4; idx += 256) {
    const int q4   = idx & 15;
    const int k    = idx >> 4;                // 0..639
    const int gate = q4 & 3;
    const int ul0  = (q4 >> 2) * 4;           // 0,4,8,12
    const int col  = gate * H_ + u0 + ul0;
    const float* src = (k < H_) ? (U + (size_t)k * G4_ + col)
                                : (W + (size_t)(k - H_) * G4_ + col);
    const f32x4 v4 = *(const f32x4*)src;
#pragma unroll
    for (int q = 0; q < 4; ++q) {
      const int ul = ul0 + q;
      const int cc = (ul >> 2) * 16 + (ul & 3) * 4 + gate;
      V[swz(cc, k)] = f2bf(v4[q]);
    }
  }

  // wave w's gate bias for tile w: unit = u0 + w*4 + l4, gate g
  float bias_r[4];
#pragma unroll
  for (int g = 0; g < 4; ++g) bias_r[g] = bias[g * H_ + u0 + w * 4 + l4];

  __syncthreads();

  const int brow = bbase + (l15 & 7);   // rows duplicated for l15>=8
  const float* xrow = x + (size_t)brow * S_ * F_ + koff + w * 32;
  const unsigned short* hrow0 = hbuf + (size_t)brow * H_ + koff;
  const int myunit = u0 + w * 4 + l4;   // this lane's (row,unit) in tile w

  float cst = 0.f;                      // c-state of (brow, myunit)

  // preload x(0) slice for this wave
  f32x4 xa = *(const f32x4*)(xrow);
  f32x4 xb = *(const f32x4*)(xrow + 4);

  for (int t = 0; t < S_; ++t) {
    // ---- x @ W first (h-independent): hides the poll below ----
    f32x4 acc[4];
#pragma unroll
    for (int tl = 0; tl < 4; ++tl) { acc[tl][0]=0.f; acc[tl][1]=0.f; acc[tl][2]=0.f; acc[tl][3]=0.f; }
    {
      const short8 bx = pack2(xa, xb);
      const int k0 = (KH + w) * 32 + koff;
#pragma unroll
      for (int tl = 0; tl < 4; ++tl) {
        const short8 a = *(const short8*)&V[swz(tl * 16 + l15, k0)];
        acc[tl] = __builtin_amdgcn_mfma_f32_16x16x32_bf16(a, bx, acc[tl], 0, 0, 0);
      }
    }

    // ---- issue x(t+1) loads now; they complete under h@U ----
    {
      const int tn = (t + 1 < S_) ? t + 1 : t;
      const float* xt = xrow + (size_t)tn * F_;
      xa = *(const f32x4*)(xt);
      xb = *(const f32x4*)(xt + 4);
    }

    // ---- wave 0 polls this group's packed flag line (1 coalesced load) ----
    if (t > 0 && w == 0) {
      const unsigned tgt = (unsigned)t;
      while (true) {
        unsigned v = __hip_atomic_load(pollp, __ATOMIC_RELAXED, __HIP_MEMORY_SCOPE_AGENT);
        if (__all((int)(v >= tgt))) break;
      }
    }
    __syncthreads();   // barrier1: h(t-1) safe to read

    // ---- this wave's h B-frags (k-steps 4w..4w+3) + h@U ----
    if (t > 0) {
      const unsigned short* hr = hrow0 + (size_t)(t & 1) * HB;
      short8 bh[4];
#pragma unroll
      for (int i = 0; i < 4; ++i) {
        union { ull u[2]; short8 s; } bb;
        const ull* hq = (const ull*)(hr + (4 * w + i) * 32);
        bb.u[0] = __hip_atomic_load(hq,     __ATOMIC_RELAXED, __HIP_MEMORY_SCOPE_AGENT);
        bb.u[1] = __hip_atomic_load(hq + 1, __ATOMIC_RELAXED, __HIP_MEMORY_SCOPE_AGENT);
        bh[i] = bb.s;
      }
#pragma unroll
      for (int i = 0; i < 4; ++i) {
        const int k0 = (4 * w + i) * 32 + koff;
#pragma unroll
        for (int tl = 0; tl < 4; ++tl) {
          const short8 a = *(const short8*)&V[swz(tl * 16 + l15, k0)];
          acc[tl] = __builtin_amdgcn_mfma_f32_16x16x32_bf16(a, bh[i], acc[tl], 0, 0, 0);
        }
      }
    }

    // ---- stage all partials; each wave reduces ITS tile ----
#pragma unroll
    for (int tl = 0; tl < 4; ++tl) R[w][tl][lane] = acc[tl];
    __syncthreads();   // barrier2: partials visible
    // (single-buffered R safe: next write gated by barrier1(t+1) > barrier3(t))

    f32x4 z;
    {
      const f32x4 r0 = R[0][w][lane], r1 = R[1][w][lane],
                  r2 = R[2][w][lane], r3 = R[3][w][lane];
#pragma unroll
      for (int g = 0; g < 4; ++g)
        z[g] = bias_r[g] + r0[g] + r1[g] + r2[g] + r3[g];
    }

    // ---- gates for (brow, myunit); h store; drain; publish; out ----
    const float ig = 1.f / (1.f + __expf(-z[0]));
    const float fg = 1.f / (1.f + __expf(-z[1]));
    const float gg = fmaxf(z[2], 0.f);             // relu candidate
    const float og = 1.f / (1.f + __expf(-z[3]));
    const float cn = fg * cst + ig * gg;
    cst = cn;
    const float hv = og * fmaxf(cn, 0.f);          // relu output activation

    if (l15 < 8)
      hbuf[(size_t)((t + 1) & 1) * HB + (size_t)brow * H_ + myunit] = f2bf(hv);
    asm volatile("s_waitcnt vmcnt(0)" ::: "memory");   // h stores at L2
    __syncthreads();   // barrier3: all 4 waves' h slices are in L2
    if (tid == 0)
      __hip_atomic_store(myflag, (unsigned)(t + 1), __ATOMIC_RELAXED, __HIP_MEMORY_SCOPE_AGENT);
    if (l15 < 8)
      out[((size_t)brow * S_ + t) * H_ + myunit] = hv;   // off the publish path
  }
}

extern "C" void kernel_launch(void* const* d_in, const int* in_sizes, int n_in,
                              void* d_out, int out_size, void* d_ws, size_t ws_size,
                              hipStream_t stream) {
  const float* x = (const float*)d_in[0];
  const float* W = (const float*)d_in[1];
  const float* U = (const float*)d_in[2];
  const float* b = (const float*)d_in[3];
  float* out = (float*)d_out;

  unsigned int*   ws_sync = (unsigned int*)d_ws;                    // ctrs(1KB) + flag lines(1KB)
  unsigned short* hbuf    = (unsigned short*)((char*)d_ws + 32768); // 2 x 64 x 512 bf16 = 128KB

  hipMemsetAsync(d_ws, 0, 32768, stream);   // zero slot ctrs + flags each launch/replay

  lstm_pers<<<dim3(256), dim3(256), 0, stream>>>(x, W, U, b, out, ws_sync, hbuf);
}